// Round 1
// baseline (518.312 us; speedup 1.0000x reference)
//
#include <hip/hip_runtime.h>

#define B_   512
#define T_   365
#define DD_  5
#define DS_  27
#define H_   256
#define ROWS 2
#define NBLK (B_ / ROWS)      // 256 blocks = 1 per CU
#define NW   8
#define NTHR (NW * 64)        // 512 threads

typedef _Float16 half4_t __attribute__((ext_vector_type(4)));
typedef float    f32x4   __attribute__((ext_vector_type(4)));

__device__ __forceinline__ float sigmoid_f(float x) {
    return 1.0f / (1.0f + __expf(-x));
}
__device__ __forceinline__ float tanh_f(float x) {
    float e = __expf(2.0f * x);
    return 1.0f - 2.0f / (e + 1.0f);
}

__global__ __launch_bounds__(NTHR, 2)
void ealstm_kernel(const float* __restrict__ xdyn,   // [B,T,DD]
                   const float* __restrict__ xstat,  // [B,DS]
                   const float* __restrict__ Wi, const float* __restrict__ bi,
                   const float* __restrict__ Wf, const float* __restrict__ bf_,
                   const float* __restrict__ Wg, const float* __restrict__ bg,
                   const float* __restrict__ Wo, const float* __restrict__ bo,
                   const float* __restrict__ Wh, const float* __restrict__ bh,
                   float* __restrict__ out)
{
    const int tid = threadIdx.x;
    const int l   = tid & 63;
    const int w   = tid >> 6;
    const int blk = blockIdx.x;
    const int b0  = blk * ROWS;

    // h double-buffer: 16 rows (MFMA M) x 264 f16 (256 cols + pad -> 528B pitch,
    // 16B-aligned rows, 2-way-max bank aliasing on A-fragment reads)
    __shared__ __align__(16) _Float16 hbuf[2][16][264];
    __shared__ float xsh[ROWS][T_ * DD_];   // all dynamic inputs for this block's rows
    __shared__ float presh[2][H_][2];       // pre-activations [mat][col][row]
    __shared__ float red[NW];

    // zero both h buffers (rows >= ROWS stay zero forever -> garbage M-rows inert)
    {
        _Float16* hz = &hbuf[0][0][0];
        for (int i = tid; i < 2 * 16 * 264; i += NTHR) hz[i] = (_Float16)0.0f;
    }
    // preload x_dynamic for this block's rows (coalesced, one-time)
    for (int i = tid; i < ROWS * T_ * DD_; i += NTHR) {
        int r   = i / (T_ * DD_);
        int rem = i - r * (T_ * DD_);
        xsh[r][rem] = xdyn[(size_t)(b0 + r) * (T_ * DD_) + rem];
    }

    // ---- load persistent B fragments (h-part weights, fp16, MFMA layout) ----
    // wave w owns output cols [w*32, w*32+32) as two 16x16 tiles, both matrices.
    const int colW = w * 32;
    const int lg   = l >> 4;     // 0..3
    const int lm   = l & 15;     // 0..15
    half4_t Bf[2][2][16];        // [mat][tile][kstep] : 128 VGPRs
    {
        const float* Wsrc0 = Wg;
        const float* Wsrc1 = Wo;
#pragma unroll
        for (int m = 0; m < 2; ++m) {
            const float* Ws = (m == 0) ? Wsrc0 : Wsrc1;
#pragma unroll
            for (int tt = 0; tt < 2; ++tt) {
#pragma unroll
                for (int ks = 0; ks < 16; ++ks) {
                    int col = colW + tt * 16 + lm;
                    int k   = ks * 16 + 4 * lg;
                    const float* p = Ws + (size_t)(DD_ + k) * H_ + col;
                    half4_t v;
#pragma unroll
                    for (int i = 0; i < 4; ++i) v[i] = (_Float16)p[(size_t)i * H_];
                    Bf[m][tt][ks] = v;
                }
            }
        }
    }

    // ---- per-thread "owner" element: (orow, oc) of this block's output ----
    const int oc   = tid & 255;
    const int orow = tid >> 8;           // 0..ROWS-1
    const int ob   = b0 + orow;

    float iG, fG;
    {
        float ai = bi[oc], af = bf_[oc];
        for (int d = 0; d < DS_; ++d) {
            float xv = xstat[ob * DS_ + d];
            ai += xv * Wi[d * H_ + oc];
            af += xv * Wf[d * H_ + oc];
        }
        iG = sigmoid_f(ai);
        fG = sigmoid_f(af);
    }
    float Wgx[DD_], Wox[DD_];
#pragma unroll
    for (int d = 0; d < DD_; ++d) {
        Wgx[d] = Wg[d * H_ + oc];
        Wox[d] = Wo[d * H_ + oc];
    }
    const float bgv = bg[oc], bov = bo[oc];

    float cst = 0.0f, hlast = 0.0f;

    half4_t Af[16];
    {
        half4_t z;
        z[0] = z[1] = z[2] = z[3] = (_Float16)0.0f;
#pragma unroll
        for (int ks = 0; ks < 16; ++ks) Af[ks] = z;
    }
    const bool areal = (lm < ROWS);   // only lanes whose A-row is a real batch row load

    __syncthreads();

    for (int t = 0; t < T_; ++t) {
        const int cur = t & 1;
        const int nxt = cur ^ 1;

        // A fragments: h[row=lm][k] ; masked lanes keep their zeros (rows 2..15)
        if (areal) {
#pragma unroll
            for (int ks = 0; ks < 16; ++ks)
                Af[ks] = *(const half4_t*)&hbuf[cur][lm][ks * 16 + 4 * lg];
        }

        f32x4 accG0 = {0.f,0.f,0.f,0.f}, accG1 = {0.f,0.f,0.f,0.f};
        f32x4 accO0 = {0.f,0.f,0.f,0.f}, accO1 = {0.f,0.f,0.f,0.f};
#pragma unroll
        for (int ks = 0; ks < 16; ++ks) {
            accG0 = __builtin_amdgcn_mfma_f32_16x16x16f16(Af[ks], Bf[0][0][ks], accG0, 0, 0, 0);
            accG1 = __builtin_amdgcn_mfma_f32_16x16x16f16(Af[ks], Bf[0][1][ks], accG1, 0, 0, 0);
            accO0 = __builtin_amdgcn_mfma_f32_16x16x16f16(Af[ks], Bf[1][0][ks], accO0, 0, 0, 0);
            accO1 = __builtin_amdgcn_mfma_f32_16x16x16f16(Af[ks], Bf[1][1][ks], accO1, 0, 0, 0);
        }

        // lanes 0..15 hold output rows 0,1 in acc regs 0,1 -> export real rows
        if (l < 16) {
            int c0 = colW + lm;
            int c1 = colW + 16 + lm;
            *(float2*)&presh[0][c0][0] = make_float2(accG0[0], accG0[1]);
            *(float2*)&presh[0][c1][0] = make_float2(accG1[0], accG1[1]);
            *(float2*)&presh[1][c0][0] = make_float2(accO0[0], accO0[1]);
            *(float2*)&presh[1][c1][0] = make_float2(accO1[0], accO1[1]);
        }
        __syncthreads();

        // elementwise: one (row,col) per thread, zero garbage work
        {
            const float* xt = &xsh[orow][t * DD_];
            float xg = bgv, xo = bov;
#pragma unroll
            for (int d = 0; d < DD_; ++d) {
                float xv = xt[d];
                xg += xv * Wgx[d];
                xo += xv * Wox[d];
            }
            float pg = presh[0][oc][orow] + xg;
            float po = presh[1][oc][orow] + xo;
            float g  = tanh_f(pg);
            float o  = sigmoid_f(po);
            cst   = fG * cst + iG * g;
            hlast = o * tanh_f(cst);
            hbuf[nxt][orow][oc] = (_Float16)hlast;
        }
        __syncthreads();
    }

    // ---- output: out[b] = sum_c h[b][c] * Wh[c] + bh ----
    float v = hlast * Wh[oc];
#pragma unroll
    for (int off = 32; off > 0; off >>= 1)
        v += __shfl_down(v, off);
    if (l == 0) red[w] = v;
    __syncthreads();
    if (tid < ROWS) {
        out[b0 + tid] = red[tid * 4 + 0] + red[tid * 4 + 1]
                      + red[tid * 4 + 2] + red[tid * 4 + 3] + bh[0];
    }
}

extern "C" void kernel_launch(void* const* d_in, const int* in_sizes, int n_in,
                              void* d_out, int out_size, void* d_ws, size_t ws_size,
                              hipStream_t stream) {
    (void)in_sizes; (void)n_in; (void)out_size; (void)d_ws; (void)ws_size;
    const float* xdyn  = (const float*)d_in[0];
    const float* xstat = (const float*)d_in[1];
    const float* Wi    = (const float*)d_in[2];
    const float* bi    = (const float*)d_in[3];
    const float* Wf    = (const float*)d_in[4];
    const float* bf    = (const float*)d_in[5];
    const float* Wg    = (const float*)d_in[6];
    const float* bg    = (const float*)d_in[7];
    const float* Wo    = (const float*)d_in[8];
    const float* bo    = (const float*)d_in[9];
    const float* Wh    = (const float*)d_in[10];
    const float* bh    = (const float*)d_in[11];
    float* out = (float*)d_out;

    hipLaunchKernelGGL(ealstm_kernel, dim3(NBLK), dim3(NTHR), 0, stream,
                       xdyn, xstat, Wi, bi, Wf, bf, Wg, bg, Wo, bo, Wh, bh, out);
}

// Round 2
// 322.787 us; speedup vs baseline: 1.6057x; 1.6057x over previous
//
#include <hip/hip_runtime.h>

#define B_   512
#define T_   365
#define DD_  5
#define DS_  27
#define H_   256
#define ROWS 2
#define NBLK (B_ / ROWS)      // 256 blocks = 1 per CU
#define NW   8
#define NTHR (NW * 64)        // 512 threads

typedef _Float16 half8_t __attribute__((ext_vector_type(8)));
typedef float    f32x4   __attribute__((ext_vector_type(4)));

#define LOG2E_ 1.4426950408889634f

__device__ __forceinline__ float sigmoid_f(float x) {
    // 1/(1+2^(-x*log2e)); rcp/exp2 HW approx, err ~1e-6
    return __builtin_amdgcn_rcpf(1.0f + __builtin_amdgcn_exp2f(-x * LOG2E_));
}
__device__ __forceinline__ float tanh_f(float x) {
    // 1 - 2/(1+2^(2x*log2e)); saturates correctly at +-inf
    return 1.0f - 2.0f * __builtin_amdgcn_rcpf(1.0f + __builtin_amdgcn_exp2f(2.0f * LOG2E_ * x));
}

__global__ __launch_bounds__(NTHR, 2)
void ealstm_kernel(const float* __restrict__ xdyn,   // [B,T,DD]
                   const float* __restrict__ xstat,  // [B,DS]
                   const float* __restrict__ Wi, const float* __restrict__ bi,
                   const float* __restrict__ Wf, const float* __restrict__ bf_,
                   const float* __restrict__ Wg, const float* __restrict__ bg,
                   const float* __restrict__ Wo, const float* __restrict__ bo,
                   const float* __restrict__ Wh, const float* __restrict__ bh,
                   float* __restrict__ out)
{
    const int tid = threadIdx.x;
    const int l   = tid & 63;
    const int w   = tid >> 6;
    const int blk = blockIdx.x;
    const int b0  = blk * ROWS;

    // h double-buffer: 16 rows (MFMA M) x 264 f16 (528B pitch, 16B-aligned rows)
    __shared__ __align__(16) _Float16 hbuf[2][16][264];
    __shared__ float xsh[ROWS][T_ * DD_];   // all dynamic inputs for this block's rows
    __shared__ float presh[2][H_][2];       // pre-activations [mat][col][row]
    __shared__ float red[NW];

    // zero both h buffers (rows >= ROWS stay zero forever -> garbage M-rows inert)
    {
        _Float16* hz = &hbuf[0][0][0];
        for (int i = tid; i < 2 * 16 * 264; i += NTHR) hz[i] = (_Float16)0.0f;
    }
    // preload x_dynamic for this block's rows (coalesced, one-time)
    for (int i = tid; i < ROWS * T_ * DD_; i += NTHR) {
        int r   = i / (T_ * DD_);
        int rem = i - r * (T_ * DD_);
        xsh[r][rem] = xdyn[(size_t)(b0 + r) * (T_ * DD_) + rem];
    }

    // ---- load persistent B fragments (h-part weights, fp16, MFMA 16x16x32 layout)
    // wave w owns output cols [w*32, w*32+32) as two 16x16 tiles, both matrices.
    // lane l holds B[k = ks*32 + 8*(l>>4) + i][col = tile_col + (l&15)], i=0..7
    const int colW = w * 32;
    const int lg   = l >> 4;     // 0..3
    const int lm   = l & 15;     // 0..15
    half8_t Bf[2][2][8];         // [mat][tile][kstep] : 128 VGPRs
    {
#pragma unroll
        for (int m = 0; m < 2; ++m) {
            const float* Ws = (m == 0) ? Wg : Wo;
#pragma unroll
            for (int tt = 0; tt < 2; ++tt) {
#pragma unroll
                for (int ks = 0; ks < 8; ++ks) {
                    int col = colW + tt * 16 + lm;
                    int k   = ks * 32 + 8 * lg;
                    const float* p = Ws + (size_t)(DD_ + k) * H_ + col;
                    half8_t v;
#pragma unroll
                    for (int i = 0; i < 8; ++i) v[i] = (_Float16)p[(size_t)i * H_];
                    Bf[m][tt][ks] = v;
                }
            }
        }
    }

    // ---- per-thread "owner" element: (orow, oc) of this block's output ----
    const int oc   = tid & 255;
    const int orow = tid >> 8;           // 0..ROWS-1
    const int ob   = b0 + orow;

    float iG, fG;
    {
        float ai = bi[oc], af = bf_[oc];
        for (int d = 0; d < DS_; ++d) {
            float xv = xstat[ob * DS_ + d];
            ai += xv * Wi[d * H_ + oc];
            af += xv * Wf[d * H_ + oc];
        }
        iG = sigmoid_f(ai);
        fG = sigmoid_f(af);
    }
    float Wgx[DD_], Wox[DD_];
#pragma unroll
    for (int d = 0; d < DD_; ++d) {
        Wgx[d] = Wg[d * H_ + oc];
        Wox[d] = Wo[d * H_ + oc];
    }
    const float bgv = bg[oc], bov = bo[oc];

    float cst = 0.0f, hlast = 0.0f;

    half8_t Af[8];
    {
        half8_t z;
#pragma unroll
        for (int i = 0; i < 8; ++i) z[i] = (_Float16)0.0f;
#pragma unroll
        for (int ks = 0; ks < 8; ++ks) Af[ks] = z;
    }
    const bool areal = (lm < ROWS);   // only lanes whose A-row is a real batch row load

    __syncthreads();

    for (int t = 0; t < T_; ++t) {
        const int cur = t & 1;
        const int nxt = cur ^ 1;

        // A fragments: h[row=lm][k = ks*32 + 8*lg + i]; masked lanes keep zeros
        if (areal) {
#pragma unroll
            for (int ks = 0; ks < 8; ++ks)
                Af[ks] = *(const half8_t*)&hbuf[cur][lm][ks * 32 + 8 * lg];
        }

        f32x4 accG0 = {0.f,0.f,0.f,0.f}, accG1 = {0.f,0.f,0.f,0.f};
        f32x4 accO0 = {0.f,0.f,0.f,0.f}, accO1 = {0.f,0.f,0.f,0.f};
#pragma unroll
        for (int ks = 0; ks < 8; ++ks) {
            accG0 = __builtin_amdgcn_mfma_f32_16x16x32_f16(Af[ks], Bf[0][0][ks], accG0, 0, 0, 0);
            accG1 = __builtin_amdgcn_mfma_f32_16x16x32_f16(Af[ks], Bf[0][1][ks], accG1, 0, 0, 0);
            accO0 = __builtin_amdgcn_mfma_f32_16x16x32_f16(Af[ks], Bf[1][0][ks], accO0, 0, 0, 0);
            accO1 = __builtin_amdgcn_mfma_f32_16x16x32_f16(Af[ks], Bf[1][1][ks], accO1, 0, 0, 0);
        }

        // lanes 0..15 hold output rows 0,1 in acc regs 0,1 -> export real rows
        if (l < 16) {
            int c0 = colW + lm;
            int c1 = colW + 16 + lm;
            *(float2*)&presh[0][c0][0] = make_float2(accG0[0], accG0[1]);
            *(float2*)&presh[0][c1][0] = make_float2(accG1[0], accG1[1]);
            *(float2*)&presh[1][c0][0] = make_float2(accO0[0], accO0[1]);
            *(float2*)&presh[1][c1][0] = make_float2(accO1[0], accO1[1]);
        }
        __syncthreads();

        // elementwise: one (row,col) per thread, zero garbage work
        {
            const float* xt = &xsh[orow][t * DD_];
            float xg = bgv, xo = bov;
#pragma unroll
            for (int d = 0; d < DD_; ++d) {
                float xv = xt[d];
                xg += xv * Wgx[d];
                xo += xv * Wox[d];
            }
            float pg = presh[0][oc][orow] + xg;
            float po = presh[1][oc][orow] + xo;
            float g  = tanh_f(pg);
            float o  = sigmoid_f(po);
            cst   = fG * cst + iG * g;
            hlast = o * tanh_f(cst);
            hbuf[nxt][orow][oc] = (_Float16)hlast;
        }
        __syncthreads();
    }

    // ---- output: out[b] = sum_c h[b][c] * Wh[c] + bh ----
    float v = hlast * Wh[oc];
#pragma unroll
    for (int off = 32; off > 0; off >>= 1)
        v += __shfl_down(v, off);
    if (l == 0) red[w] = v;
    __syncthreads();
    if (tid < ROWS) {
        out[b0 + tid] = red[tid * 4 + 0] + red[tid * 4 + 1]
                      + red[tid * 4 + 2] + red[tid * 4 + 3] + bh[0];
    }
}

extern "C" void kernel_launch(void* const* d_in, const int* in_sizes, int n_in,
                              void* d_out, int out_size, void* d_ws, size_t ws_size,
                              hipStream_t stream) {
    (void)in_sizes; (void)n_in; (void)out_size; (void)d_ws; (void)ws_size;
    const float* xdyn  = (const float*)d_in[0];
    const float* xstat = (const float*)d_in[1];
    const float* Wi    = (const float*)d_in[2];
    const float* bi    = (const float*)d_in[3];
    const float* Wf    = (const float*)d_in[4];
    const float* bf    = (const float*)d_in[5];
    const float* Wg    = (const float*)d_in[6];
    const float* bg    = (const float*)d_in[7];
    const float* Wo    = (const float*)d_in[8];
    const float* bo    = (const float*)d_in[9];
    const float* Wh    = (const float*)d_in[10];
    const float* bh    = (const float*)d_in[11];
    float* out = (float*)d_out;

    hipLaunchKernelGGL(ealstm_kernel, dim3(NBLK), dim3(NTHR), 0, stream,
                       xdyn, xstat, Wi, bi, Wf, bf, Wg, bg, Wo, bo, Wh, bh, out);
}